// Round 1
// baseline (1524.903 us; speedup 1.0000x reference)
//
#include <hip/hip_runtime.h>
#include <math.h>

#define N_NODES 100000
#define N_EDGES 600000
#define NC 41

// ---------- small utility kernels ----------
__global__ void k_fill(float* __restrict__ p, float v, int n) {
    int i = blockIdx.x * blockDim.x + threadIdx.x;
    if (i < n) p[i] = v;
}

__global__ void k_zero4(float4* __restrict__ p, int n4) {
    int i = blockIdx.x * blockDim.x + threadIdx.x;
    if (i < n4) p[i] = make_float4(0.f, 0.f, 0.f, 0.f);
}

__global__ void k_degacc(const int* __restrict__ dst, float* __restrict__ deg, int E) {
    int e = blockIdx.x * blockDim.x + threadIdx.x;
    if (e < E) unsafeAtomicAdd(&deg[dst[e]], 1.0f);
}

__global__ void k_rsqrt(float* __restrict__ p, int n) {
    int i = blockIdx.x * blockDim.x + threadIdx.x;
    if (i < n) p[i] = rsqrtf(p[i]);
}

// ---------- GEMM1: h = x @ W1   (N x 128) @ (128 x 128) ----------
// W1 fully staged in LDS (64KB). Each block handles 2 rows per iteration:
// lanes j=0..127 each own one output column; x row read uniformly (broadcast).
__global__ __launch_bounds__(256) void k_gemm1(const float* __restrict__ x,
                                               const float* __restrict__ W,
                                               float* __restrict__ h, int N) {
    __shared__ float Wl[128 * 128];
    int tid = threadIdx.x;
    for (int i = tid; i < 128 * 32; i += 256)
        ((float4*)Wl)[i] = ((const float4*)W)[i];
    __syncthreads();

    int j = tid & 127;
    int half = tid >> 7;
    for (int rp = blockIdx.x; rp < N / 2; rp += gridDim.x) {
        int r = rp * 2 + half;
        const float4* xr = (const float4*)(x + (size_t)r * 128);
        float acc = 0.f;
#pragma unroll
        for (int k4 = 0; k4 < 32; ++k4) {
            float4 v = xr[k4];
            acc = fmaf(v.x, Wl[(k4 * 4 + 0) * 128 + j], acc);
            acc = fmaf(v.y, Wl[(k4 * 4 + 1) * 128 + j], acc);
            acc = fmaf(v.z, Wl[(k4 * 4 + 2) * 128 + j], acc);
            acc = fmaf(v.w, Wl[(k4 * 4 + 3) * 128 + j], acc);
        }
        h[(size_t)r * 128 + j] = acc;
    }
}

// ---------- aggregation layer 1: B[dst] += h[src] * norm ----------
// 32 lanes per edge, float4 per lane (full 128-float row).
__global__ __launch_bounds__(256) void k_agg1(const float* __restrict__ h,
                                              float* __restrict__ out,
                                              const int* __restrict__ src,
                                              const int* __restrict__ dst,
                                              const float* __restrict__ dinv, int E) {
    int gid = blockIdx.x * 256 + threadIdx.x;
    int e = gid >> 5;
    if (e >= E) return;
    int lane = gid & 31;
    int s = src[e], d = dst[e];
    float nm = dinv[s] * dinv[d];
    float4 v = ((const float4*)(h + (size_t)s * 128))[lane];
    float* o = out + (size_t)d * 128 + lane * 4;
    unsafeAtomicAdd(o + 0, v.x * nm);
    unsafeAtomicAdd(o + 1, v.y * nm);
    unsafeAtomicAdd(o + 2, v.z * nm);
    unsafeAtomicAdd(o + 3, v.w * nm);
}

// ---------- finalize1: B = relu(B + h1 * dinv^2 + b1) ----------
__global__ void k_fin1(float* __restrict__ B, const float* __restrict__ A,
                       const float* __restrict__ dinv, const float* __restrict__ b1,
                       int N) {
    int i = blockIdx.x * blockDim.x + threadIdx.x;  // float4 index
    if (i >= N * 32) return;
    int r = i >> 5, j4 = i & 31;
    float di = dinv[r];
    float w = di * di;
    float4 a = ((const float4*)A)[i];
    float4 bb = ((float4*)B)[i];
    float4 bias = ((const float4*)b1)[j4];
    float4 o;
    o.x = fmaxf(bb.x + a.x * w + bias.x, 0.f);
    o.y = fmaxf(bb.y + a.y * w + bias.y, 0.f);
    o.z = fmaxf(bb.z + a.z * w + bias.z, 0.f);
    o.w = fmaxf(bb.w + a.w * w + bias.w, 0.f);
    ((float4*)B)[i] = o;
}

// ---------- GEMM2: h2 = B @ W2   (N x 128) @ (128 x 41), cols padded to 64 ----------
__global__ __launch_bounds__(256) void k_gemm2(const float* __restrict__ B,
                                               const float* __restrict__ W2,
                                               float* __restrict__ h2, int N) {
    __shared__ float Wl[128 * 64];
    int tid = threadIdx.x;
    for (int i = tid; i < 128 * 64; i += 256) {
        int k = i >> 6, j = i & 63;
        Wl[i] = (j < NC) ? W2[k * NC + j] : 0.f;
    }
    __syncthreads();

    int j = tid & 63, q = tid >> 6;
    for (int r0 = blockIdx.x * 4; r0 < N; r0 += gridDim.x * 4) {
        int r = r0 + q;
        const float4* br = (const float4*)(B + (size_t)r * 128);
        float acc = 0.f;
#pragma unroll
        for (int k4 = 0; k4 < 32; ++k4) {
            float4 v = br[k4];
            acc = fmaf(v.x, Wl[(k4 * 4 + 0) * 64 + j], acc);
            acc = fmaf(v.y, Wl[(k4 * 4 + 1) * 64 + j], acc);
            acc = fmaf(v.z, Wl[(k4 * 4 + 2) * 64 + j], acc);
            acc = fmaf(v.w, Wl[(k4 * 4 + 3) * 64 + j], acc);
        }
        if (j < NC) h2[(size_t)r * NC + j] = acc;
    }
}

// ---------- aggregation layer 2: out[dst] += h2[src] * norm (41 floats) ----------
__global__ __launch_bounds__(256) void k_agg2(const float* __restrict__ h2,
                                              float* __restrict__ out,
                                              const int* __restrict__ src,
                                              const int* __restrict__ dst,
                                              const float* __restrict__ dinv, int E) {
    int gid = blockIdx.x * 256 + threadIdx.x;
    int e = gid >> 6;
    if (e >= E) return;
    int lane = gid & 63;
    if (lane >= NC) return;
    int s = src[e], d = dst[e];
    float nm = dinv[s] * dinv[d];
    float v = h2[(size_t)s * NC + lane];
    unsafeAtomicAdd(&out[(size_t)d * NC + lane], v * nm);
}

// ---------- finalize2: self-loop + bias, then log_softmax per row ----------
__global__ void k_fin2(float* __restrict__ out, const float* __restrict__ h2,
                       const float* __restrict__ dinv, const float* __restrict__ b2,
                       int N) {
    int row = blockIdx.x * 4 + (threadIdx.x >> 6);
    int lane = threadIdx.x & 63;
    if (row >= N) return;
    float di = dinv[row];
    float w = di * di;
    float v = -INFINITY;
    if (lane < NC)
        v = out[(size_t)row * NC + lane] + h2[(size_t)row * NC + lane] * w + b2[lane];
    float m = v;
#pragma unroll
    for (int off = 32; off; off >>= 1) m = fmaxf(m, __shfl_xor(m, off));
    float ex = (lane < NC) ? expf(v - m) : 0.f;
    float s = ex;
#pragma unroll
    for (int off = 32; off; off >>= 1) s += __shfl_xor(s, off);
    if (lane < NC) out[(size_t)row * NC + lane] = v - m - logf(s);
}

extern "C" void kernel_launch(void* const* d_in, const int* in_sizes, int n_in,
                              void* d_out, int out_size, void* d_ws, size_t ws_size,
                              hipStream_t stream) {
    const float* x  = (const float*)d_in[0];
    const float* W1 = (const float*)d_in[1];
    const float* b1 = (const float*)d_in[2];
    const float* W2 = (const float*)d_in[3];
    const float* b2 = (const float*)d_in[4];
    const int*   ei = (const int*)d_in[5];
    const int* src = ei;
    const int* dst = ei + N_EDGES;
    float* out = (float*)d_out;

    char* ws = (char*)d_ws;
    float* dinv = (float*)ws;                       // N floats
    float* A = (float*)(ws + (1 << 19));            // N*128 floats (h1, later h2)
    float* B = A + (size_t)N_NODES * 128;           // N*128 floats (agg1 / relu out)

    // degree (init 1.0 for self-loop) -> dinv = rsqrt(deg)
    k_fill<<<(N_NODES + 255) / 256, 256, 0, stream>>>(dinv, 1.0f, N_NODES);
    k_degacc<<<(N_EDGES + 255) / 256, 256, 0, stream>>>(dst, dinv, N_EDGES);
    k_rsqrt<<<(N_NODES + 255) / 256, 256, 0, stream>>>(dinv, N_NODES);

    // layer 1
    k_gemm1<<<2048, 256, 0, stream>>>(x, W1, A, N_NODES);
    k_zero4<<<(N_NODES * 32 + 255) / 256, 256, 0, stream>>>((float4*)B, N_NODES * 32);
    k_agg1<<<(N_EDGES * 32 + 255) / 256, 256, 0, stream>>>(A, B, src, dst, dinv, N_EDGES);
    k_fin1<<<(N_NODES * 32 + 255) / 256, 256, 0, stream>>>(B, A, dinv, b1, N_NODES);

    // layer 2 (h2 reuses A)
    k_gemm2<<<2048, 256, 0, stream>>>(B, W2, A, N_NODES);
    k_zero4<<<(N_NODES * NC / 4 + 255) / 256, 256, 0, stream>>>((float4*)out, N_NODES * NC / 4);
    k_agg2<<<(N_EDGES * 64 + 255) / 256, 256, 0, stream>>>(A, out, src, dst, dinv, N_EDGES);
    k_fin2<<<(N_NODES + 3) / 4, 256, 0, stream>>>(out, A, dinv, b2, N_NODES);
}

// Round 2
// 512.511 us; speedup vs baseline: 2.9754x; 2.9754x over previous
//
#include <hip/hip_runtime.h>
#include <math.h>

#define N_NODES 100000
#define N_EDGES 600000
#define NC 41
#define NB ((N_NODES + 255) / 256)   // 391 scan blocks

// ---------- utility ----------
__global__ void k_zeroi(int* __restrict__ p, int n) {
    int i = blockIdx.x * blockDim.x + threadIdx.x;
    if (i < n) p[i] = 0;
}

__global__ void k_count(const int* __restrict__ dst, int* __restrict__ cnt, int E) {
    int e = blockIdx.x * blockDim.x + threadIdx.x;
    if (e < E) atomicAdd(&cnt[dst[e]], 1);
}

__global__ void k_dinv(const int* __restrict__ cnt, float* __restrict__ dinv, int n) {
    int i = blockIdx.x * blockDim.x + threadIdx.x;
    if (i < n) dinv[i] = rsqrtf((float)(cnt[i] + 1));  // +1 self-loop
}

// ---------- 2-level exclusive scan of cnt[] -> off[], cursor (cnt overwritten) ----------
__global__ __launch_bounds__(256) void k_blocksum(const int* __restrict__ cnt,
                                                  int* __restrict__ bsum, int n) {
    __shared__ int tmp[256];
    int t = threadIdx.x, gid = blockIdx.x * 256 + t;
    tmp[t] = (gid < n) ? cnt[gid] : 0;
    __syncthreads();
    for (int d = 128; d; d >>= 1) {
        if (t < d) tmp[t] += tmp[t + d];
        __syncthreads();
    }
    if (t == 0) bsum[blockIdx.x] = tmp[0];
}

__global__ __launch_bounds__(512) void k_scanb(int* __restrict__ bsum, int nb) {
    __shared__ int tmp[512];
    int t = threadIdx.x;
    int v = (t < nb) ? bsum[t] : 0;
    tmp[t] = v;
    __syncthreads();
    for (int d = 1; d < 512; d <<= 1) {
        int u = (t >= d) ? tmp[t - d] : 0;
        __syncthreads();
        tmp[t] += u;
        __syncthreads();
    }
    if (t < nb) bsum[t] = tmp[t] - v;  // exclusive
}

__global__ __launch_bounds__(256) void k_scanfinal(int* __restrict__ cnt,
                                                   const int* __restrict__ bsum,
                                                   int* __restrict__ off, int n) {
    __shared__ int tmp[256];
    int t = threadIdx.x, gid = blockIdx.x * 256 + t;
    int v = (gid < n) ? cnt[gid] : 0;
    tmp[t] = v;
    __syncthreads();
    for (int d = 1; d < 256; d <<= 1) {
        int u = (t >= d) ? tmp[t - d] : 0;
        __syncthreads();
        tmp[t] += u;
        __syncthreads();
    }
    int ex = tmp[t] - v + bsum[blockIdx.x];
    if (gid < n) {
        off[gid] = ex;
        cnt[gid] = ex;  // cnt becomes the scatter cursor
    }
    if (gid == 0) off[n] = N_EDGES;
}

__global__ void k_scatter(const int* __restrict__ src, const int* __restrict__ dst,
                          int* __restrict__ cursor, int* __restrict__ eidx, int E) {
    int e = blockIdx.x * blockDim.x + threadIdx.x;
    if (e >= E) return;
    int pos = atomicAdd(&cursor[dst[e]], 1);
    eidx[pos] = src[e];
}

// ---------- GEMM1: h = x @ W1   (N x 128) @ (128 x 128) ----------
__global__ __launch_bounds__(256) void k_gemm1(const float* __restrict__ x,
                                               const float* __restrict__ W,
                                               float* __restrict__ h, int N) {
    __shared__ float Wl[128 * 128];
    int tid = threadIdx.x;
    for (int i = tid; i < 128 * 32; i += 256)
        ((float4*)Wl)[i] = ((const float4*)W)[i];
    __syncthreads();

    int j = tid & 127;
    int half = tid >> 7;
    for (int rp = blockIdx.x; rp < N / 2; rp += gridDim.x) {
        int r = rp * 2 + half;
        const float4* xr = (const float4*)(x + (size_t)r * 128);
        float acc = 0.f;
#pragma unroll
        for (int k4 = 0; k4 < 32; ++k4) {
            float4 v = xr[k4];
            acc = fmaf(v.x, Wl[(k4 * 4 + 0) * 128 + j], acc);
            acc = fmaf(v.y, Wl[(k4 * 4 + 1) * 128 + j], acc);
            acc = fmaf(v.z, Wl[(k4 * 4 + 2) * 128 + j], acc);
            acc = fmaf(v.w, Wl[(k4 * 4 + 3) * 128 + j], acc);
        }
        h[(size_t)r * 128 + j] = acc;
    }
}

// ---------- gather-agg layer 1 (fused self-loop + bias + relu) ----------
// one 32-lane group per node, float4 per lane
__global__ __launch_bounds__(256) void k_gather1(const float* __restrict__ h,
                                                 float* __restrict__ B,
                                                 const int* __restrict__ off,
                                                 const int* __restrict__ eidx,
                                                 const float* __restrict__ dinv,
                                                 const float* __restrict__ b1, int N) {
    int node = blockIdx.x * 8 + (threadIdx.x >> 5);
    if (node >= N) return;
    int lane = threadIdx.x & 31;
    float di = dinv[node];
    // self-loop contribution
    float4 v = ((const float4*)(h + (size_t)node * 128))[lane];
    float w = di * di;
    float4 acc = make_float4(v.x * w, v.y * w, v.z * w, v.w * w);
    int beg = off[node], end = off[node + 1];
    for (int e = beg; e < end; ++e) {
        int s = eidx[e];
        float nm = dinv[s] * di;
        float4 u = ((const float4*)(h + (size_t)s * 128))[lane];
        acc.x = fmaf(u.x, nm, acc.x);
        acc.y = fmaf(u.y, nm, acc.y);
        acc.z = fmaf(u.z, nm, acc.z);
        acc.w = fmaf(u.w, nm, acc.w);
    }
    float4 bias = ((const float4*)b1)[lane];
    acc.x = fmaxf(acc.x + bias.x, 0.f);
    acc.y = fmaxf(acc.y + bias.y, 0.f);
    acc.z = fmaxf(acc.z + bias.z, 0.f);
    acc.w = fmaxf(acc.w + bias.w, 0.f);
    ((float4*)(B + (size_t)node * 128))[lane] = acc;
}

// ---------- GEMM2: h2 = B @ W2   (N x 128) @ (128 x 41) ----------
__global__ __launch_bounds__(256) void k_gemm2(const float* __restrict__ B,
                                               const float* __restrict__ W2,
                                               float* __restrict__ h2, int N) {
    __shared__ float Wl[128 * 64];
    int tid = threadIdx.x;
    for (int i = tid; i < 128 * 64; i += 256) {
        int k = i >> 6, j = i & 63;
        Wl[i] = (j < NC) ? W2[k * NC + j] : 0.f;
    }
    __syncthreads();

    int j = tid & 63, q = tid >> 6;
    for (int r0 = blockIdx.x * 4; r0 < N; r0 += gridDim.x * 4) {
        int r = r0 + q;
        const float4* br = (const float4*)(B + (size_t)r * 128);
        float acc = 0.f;
#pragma unroll
        for (int k4 = 0; k4 < 32; ++k4) {
            float4 v = br[k4];
            acc = fmaf(v.x, Wl[(k4 * 4 + 0) * 64 + j], acc);
            acc = fmaf(v.y, Wl[(k4 * 4 + 1) * 64 + j], acc);
            acc = fmaf(v.z, Wl[(k4 * 4 + 2) * 64 + j], acc);
            acc = fmaf(v.w, Wl[(k4 * 4 + 3) * 64 + j], acc);
        }
        if (j < NC) h2[(size_t)r * NC + j] = acc;
    }
}

// ---------- gather-agg layer 2 (fused self-loop + bias + log_softmax) ----------
// one 64-lane wave per node
__global__ __launch_bounds__(256) void k_gather2(const float* __restrict__ h2,
                                                 float* __restrict__ out,
                                                 const int* __restrict__ off,
                                                 const int* __restrict__ eidx,
                                                 const float* __restrict__ dinv,
                                                 const float* __restrict__ b2, int N) {
    int node = blockIdx.x * 4 + (threadIdx.x >> 6);
    if (node >= N) return;
    int lane = threadIdx.x & 63;
    float di = dinv[node];
    float acc = 0.f;
    if (lane < NC) acc = h2[(size_t)node * NC + lane] * di * di + b2[lane];
    int beg = off[node], end = off[node + 1];
    for (int e = beg; e < end; ++e) {
        int s = eidx[e];
        float nm = dinv[s] * di;
        if (lane < NC) acc = fmaf(h2[(size_t)s * NC + lane], nm, acc);
    }
    float v = (lane < NC) ? acc : -INFINITY;
    float m = v;
#pragma unroll
    for (int o = 32; o; o >>= 1) m = fmaxf(m, __shfl_xor(m, o));
    float ex = (lane < NC) ? expf(v - m) : 0.f;
    float s = ex;
#pragma unroll
    for (int o = 32; o; o >>= 1) s += __shfl_xor(s, o);
    if (lane < NC) out[(size_t)node * NC + lane] = v - m - logf(s);
}

extern "C" void kernel_launch(void* const* d_in, const int* in_sizes, int n_in,
                              void* d_out, int out_size, void* d_ws, size_t ws_size,
                              hipStream_t stream) {
    const float* x  = (const float*)d_in[0];
    const float* W1 = (const float*)d_in[1];
    const float* b1 = (const float*)d_in[2];
    const float* W2 = (const float*)d_in[3];
    const float* b2 = (const float*)d_in[4];
    const int*   ei = (const int*)d_in[5];
    const int* src = ei;
    const int* dst = ei + N_EDGES;
    float* out = (float*)d_out;

    char* ws = (char*)d_ws;
    int*   cnt  = (int*)ws;                          // N ints (count -> cursor)
    int*   off  = cnt + N_NODES + 32;                // N+1 ints
    int*   bsum = off + N_NODES + 32;                // NB ints (<=512)
    float* dinv = (float*)(bsum + 512);              // N floats
    int*   eidx = (int*)(dinv + N_NODES);            // E ints
    float* A = (float*)(ws + (8u << 20));            // N*128 floats (h1, later h2)
    float* B = A + (size_t)N_NODES * 128;            // N*128 floats

    // degree + CSR build
    k_zeroi<<<NB, 256, 0, stream>>>(cnt, N_NODES);
    k_count<<<(N_EDGES + 255) / 256, 256, 0, stream>>>(dst, cnt, N_EDGES);
    k_dinv<<<NB, 256, 0, stream>>>(cnt, dinv, N_NODES);
    k_blocksum<<<NB, 256, 0, stream>>>(cnt, bsum, N_NODES);
    k_scanb<<<1, 512, 0, stream>>>(bsum, NB);
    k_scanfinal<<<NB, 256, 0, stream>>>(cnt, bsum, off, N_NODES);
    k_scatter<<<(N_EDGES + 255) / 256, 256, 0, stream>>>(src, dst, cnt, eidx, N_EDGES);

    // layer 1
    k_gemm1<<<2048, 256, 0, stream>>>(x, W1, A, N_NODES);
    k_gather1<<<(N_NODES + 7) / 8, 256, 0, stream>>>(A, B, off, eidx, dinv, b1, N_NODES);

    // layer 2
    k_gemm2<<<2048, 256, 0, stream>>>(B, W2, A, N_NODES);
    k_gather2<<<(N_NODES + 3) / 4, 256, 0, stream>>>(A, out, off, eidx, dinv, b2, N_NODES);
}

// Round 3
// 323.028 us; speedup vs baseline: 4.7207x; 1.5866x over previous
//
#include <hip/hip_runtime.h>
#include <math.h>

#define N_NODES 100000
#define N_EDGES 600000
#define NC 41
#define NB ((N_NODES + 255) / 256)   // 391 scan blocks

// ---------- utility ----------
__global__ void k_zeroi(int* __restrict__ p, int n) {
    int i = blockIdx.x * blockDim.x + threadIdx.x;
    if (i < n) p[i] = 0;
}

__global__ void k_count(const int* __restrict__ dst, int* __restrict__ cnt, int E) {
    int e = blockIdx.x * blockDim.x + threadIdx.x;
    if (e < E) atomicAdd(&cnt[dst[e]], 1);
}

__global__ void k_dinv(const int* __restrict__ cnt, float* __restrict__ dinv, int n) {
    int i = blockIdx.x * blockDim.x + threadIdx.x;
    if (i < n) dinv[i] = rsqrtf((float)(cnt[i] + 1));  // +1 self-loop
}

// ---------- 2-level exclusive scan of cnt[] -> off[], cursor (cnt overwritten) ----------
__global__ __launch_bounds__(256) void k_blocksum(const int* __restrict__ cnt,
                                                  int* __restrict__ bsum, int n) {
    __shared__ int tmp[256];
    int t = threadIdx.x, gid = blockIdx.x * 256 + t;
    tmp[t] = (gid < n) ? cnt[gid] : 0;
    __syncthreads();
    for (int d = 128; d; d >>= 1) {
        if (t < d) tmp[t] += tmp[t + d];
        __syncthreads();
    }
    if (t == 0) bsum[blockIdx.x] = tmp[0];
}

__global__ __launch_bounds__(512) void k_scanb(int* __restrict__ bsum, int nb) {
    __shared__ int tmp[512];
    int t = threadIdx.x;
    int v = (t < nb) ? bsum[t] : 0;
    tmp[t] = v;
    __syncthreads();
    for (int d = 1; d < 512; d <<= 1) {
        int u = (t >= d) ? tmp[t - d] : 0;
        __syncthreads();
        tmp[t] += u;
        __syncthreads();
    }
    if (t < nb) bsum[t] = tmp[t] - v;  // exclusive
}

__global__ __launch_bounds__(256) void k_scanfinal(int* __restrict__ cnt,
                                                   const int* __restrict__ bsum,
                                                   int* __restrict__ off, int n) {
    __shared__ int tmp[256];
    int t = threadIdx.x, gid = blockIdx.x * 256 + t;
    int v = (gid < n) ? cnt[gid] : 0;
    tmp[t] = v;
    __syncthreads();
    for (int d = 1; d < 256; d <<= 1) {
        int u = (t >= d) ? tmp[t - d] : 0;
        __syncthreads();
        tmp[t] += u;
        __syncthreads();
    }
    int ex = tmp[t] - v + bsum[blockIdx.x];
    if (gid < n) {
        off[gid] = ex;
        cnt[gid] = ex;  // cnt becomes the scatter cursor
    }
    if (gid == 0) off[n] = N_EDGES;
}

__global__ void k_scatter(const int* __restrict__ src, const int* __restrict__ dst,
                          int* __restrict__ cursor, int* __restrict__ eidx, int E) {
    int e = blockIdx.x * blockDim.x + threadIdx.x;
    if (e >= E) return;
    int pos = atomicAdd(&cursor[dst[e]], 1);
    eidx[pos] = src[e];
}

// ---------- GEMM1: h = x @ W1   (N x 128) @ (128 x 128) ----------
// Register-tiled: 8 rows x 4 cols per lane; W1 fully in LDS (64 KB).
// Per k-quad: 4 ds_read_b128 feed 128 FMAs -> FMA-issue-bound.
__global__ __launch_bounds__(256) void k_gemm1(const float* __restrict__ x,
                                               const float* __restrict__ W,
                                               float* __restrict__ h, int N) {
    __shared__ float Wl[128 * 128];
    int tid = threadIdx.x;
    for (int i = tid; i < 128 * 32; i += 256)
        ((float4*)Wl)[i] = ((const float4*)W)[i];
    __syncthreads();

    int cg = tid & 31, rg = tid >> 5;
    int c0 = cg * 4;
    for (int t0 = blockIdx.x * 64; t0 < N; t0 += gridDim.x * 64) {
        int r0 = t0 + rg * 8;
        const float4* xb[8];
#pragma unroll
        for (int i = 0; i < 8; ++i) {
            int rr = r0 + i;
            if (rr >= N) rr = N - 1;  // clamp (safe reads, stores guarded)
            xb[i] = (const float4*)(x + (size_t)rr * 128);
        }
        float4 acc[8];
#pragma unroll
        for (int i = 0; i < 8; ++i) acc[i] = make_float4(0.f, 0.f, 0.f, 0.f);

        for (int k4 = 0; k4 < 32; ++k4) {
            float4 xv[8];
#pragma unroll
            for (int i = 0; i < 8; ++i) xv[i] = xb[i][k4];
#pragma unroll
            for (int kk = 0; kk < 4; ++kk) {
                float4 w = *(const float4*)&Wl[(k4 * 4 + kk) * 128 + c0];
#pragma unroll
                for (int i = 0; i < 8; ++i) {
                    float xs = (kk == 0) ? xv[i].x : (kk == 1) ? xv[i].y
                             : (kk == 2) ? xv[i].z : xv[i].w;
                    acc[i].x = fmaf(xs, w.x, acc[i].x);
                    acc[i].y = fmaf(xs, w.y, acc[i].y);
                    acc[i].z = fmaf(xs, w.z, acc[i].z);
                    acc[i].w = fmaf(xs, w.w, acc[i].w);
                }
            }
        }
#pragma unroll
        for (int i = 0; i < 8; ++i) {
            int r = r0 + i;
            if (r < N) *(float4*)(h + (size_t)r * 128 + c0) = acc[i];
        }
    }
}

// ---------- gather-agg layer 1 (fused self-loop + bias + relu) ----------
__global__ __launch_bounds__(256) void k_gather1(const float* __restrict__ h,
                                                 float* __restrict__ B,
                                                 const int* __restrict__ off,
                                                 const int* __restrict__ eidx,
                                                 const float* __restrict__ dinv,
                                                 const float* __restrict__ b1, int N) {
    int node = blockIdx.x * 8 + (threadIdx.x >> 5);
    if (node >= N) return;
    int lane = threadIdx.x & 31;
    float di = dinv[node];
    float4 v = ((const float4*)(h + (size_t)node * 128))[lane];
    float w = di * di;
    float4 acc = make_float4(v.x * w, v.y * w, v.z * w, v.w * w);
    int beg = off[node], end = off[node + 1];
    for (int e = beg; e < end; ++e) {
        int s = eidx[e];
        float nm = dinv[s] * di;
        float4 u = ((const float4*)(h + (size_t)s * 128))[lane];
        acc.x = fmaf(u.x, nm, acc.x);
        acc.y = fmaf(u.y, nm, acc.y);
        acc.z = fmaf(u.z, nm, acc.z);
        acc.w = fmaf(u.w, nm, acc.w);
    }
    float4 bias = ((const float4*)b1)[lane];
    acc.x = fmaxf(acc.x + bias.x, 0.f);
    acc.y = fmaxf(acc.y + bias.y, 0.f);
    acc.z = fmaxf(acc.z + bias.z, 0.f);
    acc.w = fmaxf(acc.w + bias.w, 0.f);
    ((float4*)(B + (size_t)node * 128))[lane] = acc;
}

// ---------- GEMM2: h2 = B @ W2   (N x 128) @ (128 x 41), stored stride 64 ----------
__global__ __launch_bounds__(256) void k_gemm2(const float* __restrict__ B,
                                               const float* __restrict__ W2,
                                               float* __restrict__ h2, int N) {
    __shared__ float Wl[128 * 64];
    int tid = threadIdx.x;
    for (int i = tid; i < 128 * 64; i += 256) {
        int k = i >> 6, j = i & 63;
        Wl[i] = (j < NC) ? W2[k * NC + j] : 0.f;
    }
    __syncthreads();

    int cg = tid & 15, rg = tid >> 4;
    int c0 = cg * 4;
    for (int t0 = blockIdx.x * 128; t0 < N; t0 += gridDim.x * 128) {
        int r0 = t0 + rg * 8;
        const float4* xb[8];
#pragma unroll
        for (int i = 0; i < 8; ++i) {
            int rr = r0 + i;
            if (rr >= N) rr = N - 1;
            xb[i] = (const float4*)(B + (size_t)rr * 128);
        }
        float4 acc[8];
#pragma unroll
        for (int i = 0; i < 8; ++i) acc[i] = make_float4(0.f, 0.f, 0.f, 0.f);

        for (int k4 = 0; k4 < 32; ++k4) {
            float4 xv[8];
#pragma unroll
            for (int i = 0; i < 8; ++i) xv[i] = xb[i][k4];
#pragma unroll
            for (int kk = 0; kk < 4; ++kk) {
                float4 w = *(const float4*)&Wl[(k4 * 4 + kk) * 64 + c0];
#pragma unroll
                for (int i = 0; i < 8; ++i) {
                    float xs = (kk == 0) ? xv[i].x : (kk == 1) ? xv[i].y
                             : (kk == 2) ? xv[i].z : xv[i].w;
                    acc[i].x = fmaf(xs, w.x, acc[i].x);
                    acc[i].y = fmaf(xs, w.y, acc[i].y);
                    acc[i].z = fmaf(xs, w.z, acc[i].z);
                    acc[i].w = fmaf(xs, w.w, acc[i].w);
                }
            }
        }
#pragma unroll
        for (int i = 0; i < 8; ++i) {
            int r = r0 + i;
            if (r < N) *(float4*)(h2 + (size_t)r * 64 + c0) = acc[i];
        }
    }
}

// ---------- gather-agg layer 2 (fused self-loop + bias + log_softmax) ----------
// one 64-lane wave per node; h2 rows have stride 64
__global__ __launch_bounds__(256) void k_gather2(const float* __restrict__ h2,
                                                 float* __restrict__ out,
                                                 const int* __restrict__ off,
                                                 const int* __restrict__ eidx,
                                                 const float* __restrict__ dinv,
                                                 const float* __restrict__ b2, int N) {
    int node = blockIdx.x * 4 + (threadIdx.x >> 6);
    if (node >= N) return;
    int lane = threadIdx.x & 63;
    float di = dinv[node];
    float acc = 0.f;
    if (lane < NC) acc = h2[(size_t)node * 64 + lane] * di * di + b2[lane];
    int beg = off[node], end = off[node + 1];
    for (int e = beg; e < end; ++e) {
        int s = eidx[e];
        float nm = dinv[s] * di;
        if (lane < NC) acc = fmaf(h2[(size_t)s * 64 + lane], nm, acc);
    }
    float v = (lane < NC) ? acc : -INFINITY;
    float m = v;
#pragma unroll
    for (int o = 32; o; o >>= 1) m = fmaxf(m, __shfl_xor(m, o));
    float ex = (lane < NC) ? expf(v - m) : 0.f;
    float s = ex;
#pragma unroll
    for (int o = 32; o; o >>= 1) s += __shfl_xor(s, o);
    if (lane < NC) out[(size_t)node * NC + lane] = v - m - logf(s);
}

extern "C" void kernel_launch(void* const* d_in, const int* in_sizes, int n_in,
                              void* d_out, int out_size, void* d_ws, size_t ws_size,
                              hipStream_t stream) {
    const float* x  = (const float*)d_in[0];
    const float* W1 = (const float*)d_in[1];
    const float* b1 = (const float*)d_in[2];
    const float* W2 = (const float*)d_in[3];
    const float* b2 = (const float*)d_in[4];
    const int*   ei = (const int*)d_in[5];
    const int* src = ei;
    const int* dst = ei + N_EDGES;
    float* out = (float*)d_out;

    char* ws = (char*)d_ws;
    int*   cnt  = (int*)ws;                          // N ints (count -> cursor)
    int*   off  = cnt + N_NODES + 32;                // N+1 ints
    int*   bsum = off + N_NODES + 32;                // NB ints (<=512)
    float* dinv = (float*)(bsum + 512);              // N floats
    int*   eidx = (int*)(dinv + N_NODES);            // E ints
    float* A = (float*)(ws + (8u << 20));            // N*128 floats (h1, later h2 stride-64)
    float* B = A + (size_t)N_NODES * 128;            // N*128 floats

    // degree + CSR build
    k_zeroi<<<NB, 256, 0, stream>>>(cnt, N_NODES);
    k_count<<<(N_EDGES + 255) / 256, 256, 0, stream>>>(dst, cnt, N_EDGES);
    k_dinv<<<NB, 256, 0, stream>>>(cnt, dinv, N_NODES);
    k_blocksum<<<NB, 256, 0, stream>>>(cnt, bsum, N_NODES);
    k_scanb<<<1, 512, 0, stream>>>(bsum, NB);
    k_scanfinal<<<NB, 256, 0, stream>>>(cnt, bsum, off, N_NODES);
    k_scatter<<<(N_EDGES + 255) / 256, 256, 0, stream>>>(src, dst, cnt, eidx, N_EDGES);

    // layer 1
    k_gemm1<<<512, 256, 0, stream>>>(x, W1, A, N_NODES);
    k_gather1<<<(N_NODES + 7) / 8, 256, 0, stream>>>(A, B, off, eidx, dinv, b1, N_NODES);

    // layer 2 (h2 reuses A with row stride 64)
    k_gemm2<<<512, 256, 0, stream>>>(B, W2, A, N_NODES);
    k_gather2<<<(N_NODES + 3) / 4, 256, 0, stream>>>(A, out, off, eidx, dinv, b2, N_NODES);
}

// Round 4
// 259.605 us; speedup vs baseline: 5.8739x; 1.2443x over previous
//
#include <hip/hip_runtime.h>
#include <math.h>

#define N_NODES 100000
#define N_EDGES 600000
#define NC 41
#define NT (N_NODES / 16)            // 6250 exact row-tiles
#define NB ((N_NODES + 255) / 256)   // scan blocks

typedef __attribute__((ext_vector_type(8))) short bf16x8;
typedef __attribute__((ext_vector_type(4))) float f32x4;

static __device__ __forceinline__ unsigned short f2b(float f) {
    unsigned u = __float_as_uint(f);
    unsigned r = ((u >> 16) & 1u) + 0x7fffu;
    return (unsigned short)((u + r) >> 16);
}
static __device__ __forceinline__ float b2f(unsigned short s) {
    return __uint_as_float(((unsigned)s) << 16);
}

// ---------- CSR build ----------
__global__ void k_zeroi(int* __restrict__ p, int n) {
    int i = blockIdx.x * blockDim.x + threadIdx.x;
    if (i < n) p[i] = 0;
}

__global__ void k_count(const int* __restrict__ dst, int* __restrict__ cnt, int E) {
    int e = blockIdx.x * blockDim.x + threadIdx.x;
    if (e < E) atomicAdd(&cnt[dst[e]], 1);
}

__global__ void k_dinv(const int* __restrict__ cnt, float* __restrict__ dinv, int n) {
    int i = blockIdx.x * blockDim.x + threadIdx.x;
    if (i < n) dinv[i] = rsqrtf((float)(cnt[i] + 1));  // +1 self-loop
}

__global__ __launch_bounds__(256) void k_blocksum(const int* __restrict__ cnt,
                                                  int* __restrict__ bsum, int n) {
    __shared__ int tmp[256];
    int t = threadIdx.x, gid = blockIdx.x * 256 + t;
    tmp[t] = (gid < n) ? cnt[gid] : 0;
    __syncthreads();
    for (int d = 128; d; d >>= 1) {
        if (t < d) tmp[t] += tmp[t + d];
        __syncthreads();
    }
    if (t == 0) bsum[blockIdx.x] = tmp[0];
}

__global__ __launch_bounds__(512) void k_scanb(int* __restrict__ bsum, int nb) {
    __shared__ int tmp[512];
    int t = threadIdx.x;
    int v = (t < nb) ? bsum[t] : 0;
    tmp[t] = v;
    __syncthreads();
    for (int d = 1; d < 512; d <<= 1) {
        int u = (t >= d) ? tmp[t - d] : 0;
        __syncthreads();
        tmp[t] += u;
        __syncthreads();
    }
    if (t < nb) bsum[t] = tmp[t] - v;
}

__global__ __launch_bounds__(256) void k_scanfinal(int* __restrict__ cnt,
                                                   const int* __restrict__ bsum,
                                                   int* __restrict__ off, int n) {
    __shared__ int tmp[256];
    int t = threadIdx.x, gid = blockIdx.x * 256 + t;
    int v = (gid < n) ? cnt[gid] : 0;
    tmp[t] = v;
    __syncthreads();
    for (int d = 1; d < 256; d <<= 1) {
        int u = (t >= d) ? tmp[t - d] : 0;
        __syncthreads();
        tmp[t] += u;
        __syncthreads();
    }
    int ex = tmp[t] - v + bsum[blockIdx.x];
    if (gid < n) {
        off[gid] = ex;
        cnt[gid] = ex;
    }
    if (gid == 0) off[n] = N_EDGES;
}

__global__ void k_scatter(const int* __restrict__ src, const int* __restrict__ dst,
                          int* __restrict__ cursor, int* __restrict__ eidx, int E) {
    int e = blockIdx.x * blockDim.x + threadIdx.x;
    if (e >= E) return;
    int pos = atomicAdd(&cursor[dst[e]], 1);
    eidx[pos] = src[e];
}

// ---------- GEMM1 (MFMA): h1 = bf16(x) @ bf16(W1), f32 acc, bf16 out ----------
// Per wave: 16-row tile x 2 col-tiles; B-frags resident in VGPRs.
// A/B frags use the SAME k-mapping -> any k-permutation error cancels.
__global__ __launch_bounds__(256) void k_gemm1(const float* __restrict__ x,
                                               const float* __restrict__ W,
                                               unsigned short* __restrict__ h) {
    __shared__ unsigned short Wt[128 * 132];  // [n][k], pad 132 to break bank conflicts
    int tid = threadIdx.x;
    for (int i = tid; i < 128 * 128; i += 256) {
        int k = i >> 7, n = i & 127;
        Wt[n * 132 + k] = f2b(W[i]);
    }
    __syncthreads();

    int l = tid & 63, w = tid >> 6;
    int lr = l & 15, g = l >> 4;

    bf16x8 bf[2][4];
#pragma unroll
    for (int c = 0; c < 2; ++c) {
        int n = (w * 2 + c) * 16 + lr;
#pragma unroll
        for (int kt = 0; kt < 4; ++kt) {
            const unsigned short* p = &Wt[n * 132 + kt * 32 + g * 4];
            short4 lo = *(const short4*)p;
            short4 hi = *(const short4*)(p + 16);
            bf16x8 f;
            f[0] = lo.x; f[1] = lo.y; f[2] = lo.z; f[3] = lo.w;
            f[4] = hi.x; f[5] = hi.y; f[6] = hi.z; f[7] = hi.w;
            bf[c][kt] = f;
        }
    }

    for (int t = blockIdx.x; t < NT; t += gridDim.x) {
        int row = t * 16 + lr;
        const float4* xr = (const float4*)(x + (size_t)row * 128);
        f32x4 acc0 = {0.f, 0.f, 0.f, 0.f};
        f32x4 acc1 = {0.f, 0.f, 0.f, 0.f};
#pragma unroll
        for (int kt = 0; kt < 4; ++kt) {
            float4 alo = xr[kt * 8 + g];
            float4 ahi = xr[kt * 8 + 4 + g];
            bf16x8 a;
            a[0] = (short)f2b(alo.x); a[1] = (short)f2b(alo.y);
            a[2] = (short)f2b(alo.z); a[3] = (short)f2b(alo.w);
            a[4] = (short)f2b(ahi.x); a[5] = (short)f2b(ahi.y);
            a[6] = (short)f2b(ahi.z); a[7] = (short)f2b(ahi.w);
            acc0 = __builtin_amdgcn_mfma_f32_16x16x32_bf16(a, bf[0][kt], acc0, 0, 0, 0);
            acc1 = __builtin_amdgcn_mfma_f32_16x16x32_bf16(a, bf[1][kt], acc1, 0, 0, 0);
        }
        // C/D: col = lane&15 (+16*ct), row = (lane>>4)*4 + reg   [HW-verified layout]
        int c0 = (w * 2) * 16 + lr;
        int rbase = t * 16 + g * 4;
#pragma unroll
        for (int i = 0; i < 4; ++i) {
            h[(size_t)(rbase + i) * 128 + c0] = f2b(acc0[i]);
            h[(size_t)(rbase + i) * 128 + c0 + 16] = f2b(acc1[i]);
        }
    }
}

// ---------- gather1: B = relu(agg(h1) + b1), bf16 in/out, 2-edge MLP ----------
__global__ __launch_bounds__(256) void k_gather1(const unsigned short* __restrict__ h,
                                                 unsigned short* __restrict__ B,
                                                 const int* __restrict__ off,
                                                 const int* __restrict__ eidx,
                                                 const float* __restrict__ dinv,
                                                 const float* __restrict__ b1, int N) {
    int node = blockIdx.x * 4 + (threadIdx.x >> 6);
    if (node >= N) return;
    int l = threadIdx.x & 63;
    int hh = l >> 5, j = l & 31;
    float di = dinv[node];
    float4 acc = make_float4(0.f, 0.f, 0.f, 0.f);
    if (hh == 0) {
        ushort4 v = ((const ushort4*)(h + (size_t)node * 128))[j];
        float wgt = di * di;
        acc.x = b2f(v.x) * wgt; acc.y = b2f(v.y) * wgt;
        acc.z = b2f(v.z) * wgt; acc.w = b2f(v.w) * wgt;
    }
    int beg = off[node], end = off[node + 1];
    for (int e = beg + hh; e < end; e += 2) {
        int s = eidx[e];
        float nm = dinv[s] * di;
        ushort4 u = ((const ushort4*)(h + (size_t)s * 128))[j];
        acc.x = fmaf(b2f(u.x), nm, acc.x);
        acc.y = fmaf(b2f(u.y), nm, acc.y);
        acc.z = fmaf(b2f(u.z), nm, acc.z);
        acc.w = fmaf(b2f(u.w), nm, acc.w);
    }
    acc.x += __shfl_xor(acc.x, 32);
    acc.y += __shfl_xor(acc.y, 32);
    acc.z += __shfl_xor(acc.z, 32);
    acc.w += __shfl_xor(acc.w, 32);
    if (hh == 0) {
        float4 bias = ((const float4*)b1)[j];
        ushort4 o;
        o.x = f2b(fmaxf(acc.x + bias.x, 0.f));
        o.y = f2b(fmaxf(acc.y + bias.y, 0.f));
        o.z = f2b(fmaxf(acc.z + bias.z, 0.f));
        o.w = f2b(fmaxf(acc.w + bias.w, 0.f));
        ((ushort4*)(B + (size_t)node * 128))[j] = o;
    }
}

// ---------- GEMM2 (MFMA): h2 = Bm @ W2 (41 cols padded to 48), stride-64 bf16 out ----------
__global__ __launch_bounds__(256) void k_gemm2(const unsigned short* __restrict__ Bm,
                                               const float* __restrict__ W2,
                                               unsigned short* __restrict__ h2) {
    __shared__ unsigned short Wt[48 * 132];
    int tid = threadIdx.x;
    for (int i = tid; i < 128 * 48; i += 256) {
        int k = i / 48, n = i % 48;
        Wt[n * 132 + k] = f2b((n < NC) ? W2[k * NC + n] : 0.f);
    }
    __syncthreads();

    int l = tid & 63, w = tid >> 6;
    int lr = l & 15, g = l >> 4;

    bf16x8 bf[3][4];
#pragma unroll
    for (int c = 0; c < 3; ++c) {
        int n = c * 16 + lr;
#pragma unroll
        for (int kt = 0; kt < 4; ++kt) {
            const unsigned short* p = &Wt[n * 132 + kt * 32 + g * 4];
            short4 lo = *(const short4*)p;
            short4 hi = *(const short4*)(p + 16);
            bf16x8 f;
            f[0] = lo.x; f[1] = lo.y; f[2] = lo.z; f[3] = lo.w;
            f[4] = hi.x; f[5] = hi.y; f[6] = hi.z; f[7] = hi.w;
            bf[c][kt] = f;
        }
    }

    for (int t = blockIdx.x * 4 + w; t < NT; t += gridDim.x * 4) {
        int row = t * 16 + lr;
        const ushort4* ar = (const ushort4*)(Bm + (size_t)row * 128);
        f32x4 a0 = {0.f, 0.f, 0.f, 0.f};
        f32x4 a1 = {0.f, 0.f, 0.f, 0.f};
        f32x4 a2 = {0.f, 0.f, 0.f, 0.f};
#pragma unroll
        for (int kt = 0; kt < 4; ++kt) {
            ushort4 lo = ar[kt * 8 + g];
            ushort4 hi = ar[kt * 8 + 4 + g];
            bf16x8 a;
            a[0] = (short)lo.x; a[1] = (short)lo.y; a[2] = (short)lo.z; a[3] = (short)lo.w;
            a[4] = (short)hi.x; a[5] = (short)hi.y; a[6] = (short)hi.z; a[7] = (short)hi.w;
            a0 = __builtin_amdgcn_mfma_f32_16x16x32_bf16(a, bf[0][kt], a0, 0, 0, 0);
            a1 = __builtin_amdgcn_mfma_f32_16x16x32_bf16(a, bf[1][kt], a1, 0, 0, 0);
            a2 = __builtin_amdgcn_mfma_f32_16x16x32_bf16(a, bf[2][kt], a2, 0, 0, 0);
        }
        int rbase = t * 16 + g * 4;
#pragma unroll
        for (int i = 0; i < 4; ++i) {
            h2[(size_t)(rbase + i) * 64 + lr]      = f2b(a0[i]);
            h2[(size_t)(rbase + i) * 64 + 16 + lr] = f2b(a1[i]);
            h2[(size_t)(rbase + i) * 64 + 32 + lr] = f2b(a2[i]);
        }
    }
}

// ---------- gather2: out = log_softmax(agg(h2) + b2), 2-edge MLP ----------
__global__ __launch_bounds__(256) void k_gather2(const unsigned short* __restrict__ h2,
                                                 float* __restrict__ out,
                                                 const int* __restrict__ off,
                                                 const int* __restrict__ eidx,
                                                 const float* __restrict__ dinv,
                                                 const float* __restrict__ b2, int N) {
    int node = blockIdx.x * 4 + (threadIdx.x >> 6);
    if (node >= N) return;
    int l = threadIdx.x & 63;
    int hh = l >> 5, j = l & 31;  // j<24: cols 2j, 2j+1 (48-wide padded rows)
    bool act = (j < 24);
    float di = dinv[node];
    float ax = 0.f, ay = 0.f;
    if (hh == 0 && act) {
        unsigned u = *(const unsigned*)(h2 + (size_t)node * 64 + 2 * j);
        float wgt = di * di;
        ax = b2f((unsigned short)(u & 0xffff)) * wgt;
        ay = b2f((unsigned short)(u >> 16)) * wgt;
    }
    int beg = off[node], end = off[node + 1];
    for (int e = beg + hh; e < end; e += 2) {
        int s = eidx[e];
        float nm = dinv[s] * di;
        if (act) {
            unsigned u = *(const unsigned*)(h2 + (size_t)s * 64 + 2 * j);
            ax = fmaf(b2f((unsigned short)(u & 0xffff)), nm, ax);
            ay = fmaf(b2f((unsigned short)(u >> 16)), nm, ay);
        }
    }
    ax += __shfl_xor(ax, 32);
    ay += __shfl_xor(ay, 32);
    float v0 = -INFINITY, v1 = -INFINITY;
    if (2 * j < NC) v0 = ax + b2[2 * j];
    if (2 * j + 1 < NC) v1 = ay + b2[2 * j + 1];
    float m = fmaxf(v0, v1);
#pragma unroll
    for (int o = 16; o; o >>= 1) m = fmaxf(m, __shfl_xor(m, o));
    float s = ((2 * j < NC) ? expf(v0 - m) : 0.f) + ((2 * j + 1 < NC) ? expf(v1 - m) : 0.f);
#pragma unroll
    for (int o = 16; o; o >>= 1) s += __shfl_xor(s, o);
    float lg = logf(s);
    if (hh == 0 && 2 * j < NC) {
        out[(size_t)node * NC + 2 * j] = v0 - m - lg;
        if (2 * j + 1 < NC) out[(size_t)node * NC + 2 * j + 1] = v1 - m - lg;
    }
}

extern "C" void kernel_launch(void* const* d_in, const int* in_sizes, int n_in,
                              void* d_out, int out_size, void* d_ws, size_t ws_size,
                              hipStream_t stream) {
    const float* x  = (const float*)d_in[0];
    const float* W1 = (const float*)d_in[1];
    const float* b1 = (const float*)d_in[2];
    const float* W2 = (const float*)d_in[3];
    const float* b2 = (const float*)d_in[4];
    const int*   ei = (const int*)d_in[5];
    const int* src = ei;
    const int* dst = ei + N_EDGES;
    float* out = (float*)d_out;

    char* ws = (char*)d_ws;
    int*   cnt  = (int*)ws;
    int*   off  = cnt + N_NODES + 32;
    int*   bsum = off + N_NODES + 32;
    float* dinv = (float*)(bsum + 512);
    int*   eidx = (int*)(dinv + N_NODES);
    unsigned short* h1 = (unsigned short*)(ws + (8u << 20));   // N*128 bf16
    unsigned short* Bm = h1 + (size_t)N_NODES * 128;           // N*128 bf16
    unsigned short* h2 = Bm + (size_t)N_NODES * 128;           // N*64 bf16

    // CSR build
    k_zeroi<<<NB, 256, 0, stream>>>(cnt, N_NODES);
    k_count<<<(N_EDGES + 255) / 256, 256, 0, stream>>>(dst, cnt, N_EDGES);
    k_dinv<<<NB, 256, 0, stream>>>(cnt, dinv, N_NODES);
    k_blocksum<<<NB, 256, 0, stream>>>(cnt, bsum, N_NODES);
    k_scanb<<<1, 512, 0, stream>>>(bsum, NB);
    k_scanfinal<<<NB, 256, 0, stream>>>(cnt, bsum, off, N_NODES);
    k_scatter<<<(N_EDGES + 255) / 256, 256, 0, stream>>>(src, dst, cnt, eidx, N_EDGES);

    // layer 1
    k_gemm1<<<1024, 256, 0, stream>>>(x, W1, h1);
    k_gather1<<<(N_NODES + 3) / 4, 256, 0, stream>>>(h1, Bm, off, eidx, dinv, b1, N_NODES);

    // layer 2
    k_gemm2<<<1024, 256, 0, stream>>>(Bm, W2, h2);
    k_gather2<<<(N_NODES + 3) / 4, 256, 0, stream>>>(h2, out, off, eidx, dinv, b2, N_NODES);
}

// Round 5
// 232.325 us; speedup vs baseline: 6.5637x; 1.1174x over previous
//
#include <hip/hip_runtime.h>
#include <math.h>

#define N_NODES 100000
#define N_EDGES 600000
#define NC 41
#define NT (N_NODES / 16)            // 6250 exact row-tiles
#define NB ((N_NODES + 255) / 256)   // scan blocks

typedef __attribute__((ext_vector_type(8))) short bf16x8;
typedef __attribute__((ext_vector_type(8))) unsigned short u16x8;
typedef __attribute__((ext_vector_type(4))) float f32x4;

static __device__ __forceinline__ unsigned short f2b(float f) {
    unsigned u = __float_as_uint(f);
    unsigned r = ((u >> 16) & 1u) + 0x7fffu;
    return (unsigned short)((u + r) >> 16);
}
static __device__ __forceinline__ float b2f(unsigned short s) {
    return __uint_as_float(((unsigned)s) << 16);
}

// ---------- CSR build ----------
__global__ void k_zeroi(int* __restrict__ p, int n) {
    int i = blockIdx.x * blockDim.x + threadIdx.x;
    if (i < n) p[i] = 0;
}

__global__ void k_count(const int* __restrict__ dst, int* __restrict__ cnt, int E) {
    int e = blockIdx.x * blockDim.x + threadIdx.x;
    if (e < E) atomicAdd(&cnt[dst[e]], 1);
}

// blocksum + dinv fused (both read cnt)
__global__ __launch_bounds__(256) void k_blocksum(const int* __restrict__ cnt,
                                                  int* __restrict__ bsum,
                                                  float* __restrict__ dinv, int n) {
    __shared__ int tmp[256];
    int t = threadIdx.x, gid = blockIdx.x * 256 + t;
    int v = (gid < n) ? cnt[gid] : 0;
    if (gid < n) dinv[gid] = rsqrtf((float)(v + 1));  // +1 self-loop
    tmp[t] = v;
    __syncthreads();
    for (int d = 128; d; d >>= 1) {
        if (t < d) tmp[t] += tmp[t + d];
        __syncthreads();
    }
    if (t == 0) bsum[blockIdx.x] = tmp[0];
}

__global__ __launch_bounds__(512) void k_scanb(int* __restrict__ bsum, int nb) {
    __shared__ int tmp[512];
    int t = threadIdx.x;
    int v = (t < nb) ? bsum[t] : 0;
    tmp[t] = v;
    __syncthreads();
    for (int d = 1; d < 512; d <<= 1) {
        int u = (t >= d) ? tmp[t - d] : 0;
        __syncthreads();
        tmp[t] += u;
        __syncthreads();
    }
    if (t < nb) bsum[t] = tmp[t] - v;
}

__global__ __launch_bounds__(256) void k_scanfinal(int* __restrict__ cnt,
                                                   const int* __restrict__ bsum,
                                                   int* __restrict__ off, int n) {
    __shared__ int tmp[256];
    int t = threadIdx.x, gid = blockIdx.x * 256 + t;
    int v = (gid < n) ? cnt[gid] : 0;
    tmp[t] = v;
    __syncthreads();
    for (int d = 1; d < 256; d <<= 1) {
        int u = (t >= d) ? tmp[t - d] : 0;
        __syncthreads();
        tmp[t] += u;
        __syncthreads();
    }
    int ex = tmp[t] - v + bsum[blockIdx.x];
    if (gid < n) {
        off[gid] = ex;
        cnt[gid] = ex;
    }
    if (gid == 0) off[n] = N_EDGES;
}

__global__ void k_scatter(const int* __restrict__ src, const int* __restrict__ dst,
                          int* __restrict__ cursor, int* __restrict__ eidx, int E) {
    int e = blockIdx.x * blockDim.x + threadIdx.x;
    if (e >= E) return;
    int pos = atomicAdd(&cursor[dst[e]], 1);
    eidx[pos] = src[e];
}

// ---------- GEMM1 (MFMA): h1' = dinv[r] * (bf16(x) @ bf16(W1)), bf16 out ----------
__global__ __launch_bounds__(256) void k_gemm1(const float* __restrict__ x,
                                               const float* __restrict__ W,
                                               const float* __restrict__ dinv,
                                               unsigned short* __restrict__ h) {
    __shared__ unsigned short Wt[128 * 132];  // [n][k], pad to break bank conflicts
    int tid = threadIdx.x;
    for (int i = tid; i < 128 * 128; i += 256) {
        int k = i >> 7, n = i & 127;
        Wt[n * 132 + k] = f2b(W[i]);
    }
    __syncthreads();

    int l = tid & 63, w = tid >> 6;
    int lr = l & 15, g = l >> 4;

    bf16x8 bf[2][4];
#pragma unroll
    for (int c = 0; c < 2; ++c) {
        int n = (w * 2 + c) * 16 + lr;
#pragma unroll
        for (int kt = 0; kt < 4; ++kt) {
            const unsigned short* p = &Wt[n * 132 + kt * 32 + g * 4];
            short4 lo = *(const short4*)p;
            short4 hi = *(const short4*)(p + 16);
            bf16x8 f;
            f[0] = lo.x; f[1] = lo.y; f[2] = lo.z; f[3] = lo.w;
            f[4] = hi.x; f[5] = hi.y; f[6] = hi.z; f[7] = hi.w;
            bf[c][kt] = f;
        }
    }

    for (int t = blockIdx.x; t < NT; t += gridDim.x) {
        int row = t * 16 + lr;
        const float4* xr = (const float4*)(x + (size_t)row * 128);
        f32x4 acc0 = {0.f, 0.f, 0.f, 0.f};
        f32x4 acc1 = {0.f, 0.f, 0.f, 0.f};
#pragma unroll
        for (int kt = 0; kt < 4; ++kt) {
            float4 alo = xr[kt * 8 + g];
            float4 ahi = xr[kt * 8 + 4 + g];
            bf16x8 a;
            a[0] = (short)f2b(alo.x); a[1] = (short)f2b(alo.y);
            a[2] = (short)f2b(alo.z); a[3] = (short)f2b(alo.w);
            a[4] = (short)f2b(ahi.x); a[5] = (short)f2b(ahi.y);
            a[6] = (short)f2b(ahi.z); a[7] = (short)f2b(ahi.w);
            acc0 = __builtin_amdgcn_mfma_f32_16x16x32_bf16(a, bf[0][kt], acc0, 0, 0, 0);
            acc1 = __builtin_amdgcn_mfma_f32_16x16x32_bf16(a, bf[1][kt], acc1, 0, 0, 0);
        }
        int c0 = (w * 2) * 16 + lr;
        int rbase = t * 16 + g * 4;
#pragma unroll
        for (int i = 0; i < 4; ++i) {
            float dv = dinv[rbase + i];
            h[(size_t)(rbase + i) * 128 + c0] = f2b(acc0[i] * dv);
            h[(size_t)(rbase + i) * 128 + c0 + 16] = f2b(acc1[i] * dv);
        }
    }
}

// ---------- gather1: Bm = relu(di * (self + sum h1'[s]) + b1) ----------
// 16-lane quarters: 4 edges in flight, ushort8 (16B) per lane.
__global__ __launch_bounds__(256) void k_gather1(const unsigned short* __restrict__ h,
                                                 unsigned short* __restrict__ B,
                                                 const int* __restrict__ off,
                                                 const int* __restrict__ eidx,
                                                 const float* __restrict__ dinv,
                                                 const float* __restrict__ b1, int N) {
    int node = blockIdx.x * 4 + (threadIdx.x >> 6);
    if (node >= N) return;
    int l = threadIdx.x & 63;
    int q = l >> 4, j = l & 15;
    float di = dinv[node];
    float acc[8];
#pragma unroll
    for (int i = 0; i < 8; ++i) acc[i] = 0.f;
    if (q == 0) {
        u16x8 v = *(const u16x8*)(h + (size_t)node * 128 + j * 8);
#pragma unroll
        for (int i = 0; i < 8; ++i) acc[i] = b2f(v[i]);
    }
    int end = off[node + 1];
    int e = off[node] + q;
    int s = (e < end) ? eidx[e] : -1;
    while (s >= 0) {
        e += 4;
        int sn = (e < end) ? eidx[e] : -1;
        u16x8 u = *(const u16x8*)(h + (size_t)s * 128 + j * 8);
#pragma unroll
        for (int i = 0; i < 8; ++i) acc[i] += b2f(u[i]);
        s = sn;
    }
#pragma unroll
    for (int i = 0; i < 8; ++i) acc[i] += __shfl_xor(acc[i], 16);
#pragma unroll
    for (int i = 0; i < 8; ++i) acc[i] += __shfl_xor(acc[i], 32);
    if (q == 0) {
        float4 blo = ((const float4*)b1)[j * 2];
        float4 bhi = ((const float4*)b1)[j * 2 + 1];
        u16x8 o;
        o[0] = f2b(fmaxf(acc[0] * di + blo.x, 0.f));
        o[1] = f2b(fmaxf(acc[1] * di + blo.y, 0.f));
        o[2] = f2b(fmaxf(acc[2] * di + blo.z, 0.f));
        o[3] = f2b(fmaxf(acc[3] * di + blo.w, 0.f));
        o[4] = f2b(fmaxf(acc[4] * di + bhi.x, 0.f));
        o[5] = f2b(fmaxf(acc[5] * di + bhi.y, 0.f));
        o[6] = f2b(fmaxf(acc[6] * di + bhi.z, 0.f));
        o[7] = f2b(fmaxf(acc[7] * di + bhi.w, 0.f));
        *(u16x8*)(B + (size_t)node * 128 + j * 8) = o;
    }
}

// ---------- GEMM2 (MFMA): h2' = dinv[r] * (Bm @ W2), 48-pad, stride-64 bf16 out ----------
__global__ __launch_bounds__(256) void k_gemm2(const unsigned short* __restrict__ Bm,
                                               const float* __restrict__ W2,
                                               const float* __restrict__ dinv,
                                               unsigned short* __restrict__ h2) {
    __shared__ unsigned short Wt[48 * 132];
    int tid = threadIdx.x;
    for (int i = tid; i < 128 * 48; i += 256) {
        int k = i / 48, n = i % 48;
        Wt[n * 132 + k] = f2b((n < NC) ? W2[k * NC + n] : 0.f);
    }
    __syncthreads();

    int l = tid & 63, w = tid >> 6;
    int lr = l & 15, g = l >> 4;

    bf16x8 bf[3][4];
#pragma unroll
    for (int c = 0; c < 3; ++c) {
        int n = c * 16 + lr;
#pragma unroll
        for (int kt = 0; kt < 4; ++kt) {
            const unsigned short* p = &Wt[n * 132 + kt * 32 + g * 4];
            short4 lo = *(const short4*)p;
            short4 hi = *(const short4*)(p + 16);
            bf16x8 f;
            f[0] = lo.x; f[1] = lo.y; f[2] = lo.z; f[3] = lo.w;
            f[4] = hi.x; f[5] = hi.y; f[6] = hi.z; f[7] = hi.w;
            bf[c][kt] = f;
        }
    }

    for (int t = blockIdx.x * 4 + w; t < NT; t += gridDim.x * 4) {
        int row = t * 16 + lr;
        const ushort4* ar = (const ushort4*)(Bm + (size_t)row * 128);
        f32x4 a0 = {0.f, 0.f, 0.f, 0.f};
        f32x4 a1 = {0.f, 0.f, 0.f, 0.f};
        f32x4 a2 = {0.f, 0.f, 0.f, 0.f};
#pragma unroll
        for (int kt = 0; kt < 4; ++kt) {
            ushort4 lo = ar[kt * 8 + g];
            ushort4 hi = ar[kt * 8 + 4 + g];
            bf16x8 a;
            a[0] = (short)lo.x; a[1] = (short)lo.y; a[2] = (short)lo.z; a[3] = (short)lo.w;
            a[4] = (short)hi.x; a[5] = (short)hi.y; a[6] = (short)hi.z; a[7] = (short)hi.w;
            a0 = __builtin_amdgcn_mfma_f32_16x16x32_bf16(a, bf[0][kt], a0, 0, 0, 0);
            a1 = __builtin_amdgcn_mfma_f32_16x16x32_bf16(a, bf[1][kt], a1, 0, 0, 0);
            a2 = __builtin_amdgcn_mfma_f32_16x16x32_bf16(a, bf[2][kt], a2, 0, 0, 0);
        }
        int rbase = t * 16 + g * 4;
#pragma unroll
        for (int i = 0; i < 4; ++i) {
            float dv = dinv[rbase + i];
            h2[(size_t)(rbase + i) * 64 + lr]      = f2b(a0[i] * dv);
            h2[(size_t)(rbase + i) * 64 + 16 + lr] = f2b(a1[i] * dv);
            h2[(size_t)(rbase + i) * 64 + 32 + lr] = f2b(a2[i] * dv);
        }
    }
}

// ---------- gather2: out = log_softmax(di * (self + sum h2'[s]) + b2) ----------
// 8-lane groups: 8 edges in flight, lane j<6 loads ushort8 (8 cols).
__global__ __launch_bounds__(256) void k_gather2(const unsigned short* __restrict__ h2,
                                                 float* __restrict__ out,
                                                 const int* __restrict__ off,
                                                 const int* __restrict__ eidx,
                                                 const float* __restrict__ dinv,
                                                 const float* __restrict__ b2, int N) {
    int node = blockIdx.x * 4 + (threadIdx.x >> 6);
    if (node >= N) return;
    int l = threadIdx.x & 63;
    int g = l >> 3, j = l & 7;
    bool act = (j < 6);
    float di = dinv[node];
    float acc[8];
#pragma unroll
    for (int i = 0; i < 8; ++i) acc[i] = 0.f;
    if (g == 0 && act) {
        u16x8 v = *(const u16x8*)(h2 + (size_t)node * 64 + j * 8);
#pragma unroll
        for (int i = 0; i < 8; ++i) acc[i] = b2f(v[i]);
    }
    int end = off[node + 1];
    int e = off[node] + g;
    int s = (e < end) ? eidx[e] : -1;
    while (s >= 0) {
        e += 8;
        int sn = (e < end) ? eidx[e] : -1;
        if (act) {
            u16x8 u = *(const u16x8*)(h2 + (size_t)s * 64 + j * 8);
#pragma unroll
            for (int i = 0; i < 8; ++i) acc[i] += b2f(u[i]);
        }
        s = sn;
    }
#pragma unroll
    for (int i = 0; i < 8; ++i) acc[i] += __shfl_xor(acc[i], 8);
#pragma unroll
    for (int i = 0; i < 8; ++i) acc[i] += __shfl_xor(acc[i], 16);
#pragma unroll
    for (int i = 0; i < 8; ++i) acc[i] += __shfl_xor(acc[i], 32);
    // all lanes now hold identical column-group sums
    int c0 = j * 8;
    float vv[8];
#pragma unroll
    for (int i = 0; i < 8; ++i)
        vv[i] = (act && c0 + i < NC) ? acc[i] * di + b2[c0 + i] : -INFINITY;
    float m = vv[0];
#pragma unroll
    for (int i = 1; i < 8; ++i) m = fmaxf(m, vv[i]);
#pragma unroll
    for (int o = 4; o; o >>= 1) m = fmaxf(m, __shfl_xor(m, o));
    float sm = 0.f;
#pragma unroll
    for (int i = 0; i < 8; ++i) sm += (act && c0 + i < NC) ? expf(vv[i] - m) : 0.f;
#pragma unroll
    for (int o = 4; o; o >>= 1) sm += __shfl_xor(sm, o);
    float lg = logf(sm);
    if (g == 0 && act) {
#pragma unroll
        for (int i = 0; i < 8; ++i) {
            int c = c0 + i;
            if (c < NC) out[(size_t)node * NC + c] = vv[i] - m - lg;
        }
    }
}

extern "C" void kernel_launch(void* const* d_in, const int* in_sizes, int n_in,
                              void* d_out, int out_size, void* d_ws, size_t ws_size,
                              hipStream_t stream) {
    const float* x  = (const float*)d_in[0];
    const float* W1 = (const float*)d_in[1];
    const float* b1 = (const float*)d_in[2];
    const float* W2 = (const float*)d_in[3];
    const float* b2 = (const float*)d_in[4];
    const int*   ei = (const int*)d_in[5];
    const int* src = ei;
    const int* dst = ei + N_EDGES;
    float* out = (float*)d_out;

    char* ws = (char*)d_ws;
    int*   cnt  = (int*)ws;
    int*   off  = cnt + N_NODES + 32;
    int*   bsum = off + N_NODES + 32;
    float* dinv = (float*)(bsum + 512);
    int*   eidx = (int*)(dinv + N_NODES);
    unsigned short* h1 = (unsigned short*)(ws + (8u << 20));   // N*128 bf16 (pre-scaled)
    unsigned short* Bm = h1 + (size_t)N_NODES * 128;           // N*128 bf16
    unsigned short* h2 = Bm + (size_t)N_NODES * 128;           // N*64 bf16 (pre-scaled)

    // CSR build
    k_zeroi<<<NB, 256, 0, stream>>>(cnt, N_NODES);
    k_count<<<(N_EDGES + 255) / 256, 256, 0, stream>>>(dst, cnt, N_EDGES);
    k_blocksum<<<NB, 256, 0, stream>>>(cnt, bsum, dinv, N_NODES);
    k_scanb<<<1, 512, 0, stream>>>(bsum, NB);
    k_scanfinal<<<NB, 256, 0, stream>>>(cnt, bsum, off, N_NODES);
    k_scatter<<<(N_EDGES + 255) / 256, 256, 0, stream>>>(src, dst, cnt, eidx, N_EDGES);

    // layer 1
    k_gemm1<<<1024, 256, 0, stream>>>(x, W1, dinv, h1);
    k_gather1<<<(N_NODES + 3) / 4, 256, 0, stream>>>(h1, Bm, off, eidx, dinv, b1, N_NODES);

    // layer 2
    k_gemm2<<<1024, 256, 0, stream>>>(Bm, W2, dinv, h2);
    k_gather2<<<(N_NODES + 3) / 4, 256, 0, stream>>>(h2, out, off, eidx, dinv, b2, N_NODES);
}

// Round 6
// 191.016 us; speedup vs baseline: 7.9831x; 1.2163x over previous
//
#include <hip/hip_runtime.h>
#include <math.h>

#define N_NODES 100000
#define N_EDGES 600000
#define NC 41
#define NT (N_NODES / 16)            // 6250 exact 16-node tiles
#define NB ((N_NODES + 255) / 256)   // scan blocks

typedef __attribute__((ext_vector_type(8))) short bf16x8;
typedef __attribute__((ext_vector_type(8))) unsigned short u16x8;
typedef __attribute__((ext_vector_type(4))) float f32x4;

static __device__ __forceinline__ unsigned short f2b(float f) {
    unsigned u = __float_as_uint(f);
    unsigned r = ((u >> 16) & 1u) + 0x7fffu;
    return (unsigned short)((u + r) >> 16);
}
static __device__ __forceinline__ float b2f(unsigned short s) {
    return __uint_as_float(((unsigned)s) << 16);
}
static __device__ __forceinline__ u16x8 zero8() {
    u16x8 z;
#pragma unroll
    for (int i = 0; i < 8; ++i) z[i] = 0;
    return z;
}

// ---------- CSR build ----------
__global__ void k_count(const int* __restrict__ dst, int* __restrict__ cnt, int E) {
    int e = blockIdx.x * blockDim.x + threadIdx.x;
    if (e < E) atomicAdd(&cnt[dst[e]], 1);
}

__global__ __launch_bounds__(256) void k_blocksum(const int* __restrict__ cnt,
                                                  int* __restrict__ bsum,
                                                  float* __restrict__ dinv, int n) {
    __shared__ int tmp[256];
    int t = threadIdx.x, gid = blockIdx.x * 256 + t;
    int v = (gid < n) ? cnt[gid] : 0;
    if (gid < n) dinv[gid] = rsqrtf((float)(v + 1));  // +1 self-loop
    tmp[t] = v;
    __syncthreads();
    for (int d = 128; d; d >>= 1) {
        if (t < d) tmp[t] += tmp[t + d];
        __syncthreads();
    }
    if (t == 0) bsum[blockIdx.x] = tmp[0];
}

__global__ __launch_bounds__(512) void k_scanb(int* __restrict__ bsum, int nb) {
    __shared__ int tmp[512];
    int t = threadIdx.x;
    int v = (t < nb) ? bsum[t] : 0;
    tmp[t] = v;
    __syncthreads();
    for (int d = 1; d < 512; d <<= 1) {
        int u = (t >= d) ? tmp[t - d] : 0;
        __syncthreads();
        tmp[t] += u;
        __syncthreads();
    }
    if (t < nb) bsum[t] = tmp[t] - v;
}

__global__ __launch_bounds__(256) void k_scanfinal(int* __restrict__ cnt,
                                                   const int* __restrict__ bsum,
                                                   int* __restrict__ off, int n) {
    __shared__ int tmp[256];
    int t = threadIdx.x, gid = blockIdx.x * 256 + t;
    int v = (gid < n) ? cnt[gid] : 0;
    tmp[t] = v;
    __syncthreads();
    for (int d = 1; d < 256; d <<= 1) {
        int u = (t >= d) ? tmp[t - d] : 0;
        __syncthreads();
        tmp[t] += u;
        __syncthreads();
    }
    int ex = tmp[t] - v + bsum[blockIdx.x];
    if (gid < n) {
        off[gid] = ex;
        cnt[gid] = ex;
    }
    if (gid == 0) off[n] = N_EDGES;
}

__global__ void k_scatter(const int* __restrict__ src, const int* __restrict__ dst,
                          int* __restrict__ cursor, int* __restrict__ eidx, int E) {
    int e = blockIdx.x * blockDim.x + threadIdx.x;
    if (e >= E) return;
    int pos = atomicAdd(&cursor[dst[e]], 1);
    eidx[pos] = src[e];
}

// ---------- GEMM1 (MFMA): h1' = dinv[r] * (bf16(x) @ bf16(W1)), bf16 out ----------
__global__ __launch_bounds__(256) void k_gemm1(const float* __restrict__ x,
                                               const float* __restrict__ W,
                                               const float* __restrict__ dinv,
                                               unsigned short* __restrict__ h) {
    __shared__ unsigned short Wt[128 * 132];  // [n][k], padded
    int tid = threadIdx.x;
    for (int i = tid; i < 128 * 128; i += 256) {
        int k = i >> 7, n = i & 127;
        Wt[n * 132 + k] = f2b(W[i]);
    }
    __syncthreads();

    int l = tid & 63, w = tid >> 6;
    int lr = l & 15, g = l >> 4;

    bf16x8 bf[2][4];
#pragma unroll
    for (int c = 0; c < 2; ++c) {
        int n = (w * 2 + c) * 16 + lr;
#pragma unroll
        for (int kt = 0; kt < 4; ++kt) {
            const unsigned short* p = &Wt[n * 132 + kt * 32 + g * 4];
            short4 lo = *(const short4*)p;
            short4 hi = *(const short4*)(p + 16);
            bf16x8 f;
            f[0] = lo.x; f[1] = lo.y; f[2] = lo.z; f[3] = lo.w;
            f[4] = hi.x; f[5] = hi.y; f[6] = hi.z; f[7] = hi.w;
            bf[c][kt] = f;
        }
    }

    for (int t = blockIdx.x; t < NT; t += gridDim.x) {
        int row = t * 16 + lr;
        const float4* xr = (const float4*)(x + (size_t)row * 128);
        f32x4 acc0 = {0.f, 0.f, 0.f, 0.f};
        f32x4 acc1 = {0.f, 0.f, 0.f, 0.f};
#pragma unroll
        for (int kt = 0; kt < 4; ++kt) {
            float4 alo = xr[kt * 8 + g];
            float4 ahi = xr[kt * 8 + 4 + g];
            bf16x8 a;
            a[0] = (short)f2b(alo.x); a[1] = (short)f2b(alo.y);
            a[2] = (short)f2b(alo.z); a[3] = (short)f2b(alo.w);
            a[4] = (short)f2b(ahi.x); a[5] = (short)f2b(ahi.y);
            a[6] = (short)f2b(ahi.z); a[7] = (short)f2b(ahi.w);
            acc0 = __builtin_amdgcn_mfma_f32_16x16x32_bf16(a, bf[0][kt], acc0, 0, 0, 0);
            acc1 = __builtin_amdgcn_mfma_f32_16x16x32_bf16(a, bf[1][kt], acc1, 0, 0, 0);
        }
        int c0 = (w * 2) * 16 + lr;
        int rbase = t * 16 + g * 4;
#pragma unroll
        for (int i = 0; i < 4; ++i) {
            float dv = dinv[rbase + i];
            h[(size_t)(rbase + i) * 128 + c0] = f2b(acc0[i] * dv);
            h[(size_t)(rbase + i) * 128 + c0 + 16] = f2b(acc1[i] * dv);
        }
    }
}

// ---------- fused agg1 + GEMM2: h2' = dinv * (relu(agg(h1')+b1) @ W2) ----------
// Block: 4 waves x 4 nodes/wave (16-lane group per node, no shuffle reduce).
// Aggregated rows staged in LDS, then 16x48 MFMA with W2 (48-pad).
__global__ __launch_bounds__(256, 8) void k_agg1mm(const unsigned short* __restrict__ h,
                                                   const float* __restrict__ W2,
                                                   const float* __restrict__ dinv,
                                                   const float* __restrict__ b1,
                                                   const int* __restrict__ off,
                                                   const int* __restrict__ eidx,
                                                   unsigned short* __restrict__ h2) {
    __shared__ unsigned short Wt[48 * 132];   // W2^T bf16, padded
    __shared__ unsigned short rows[16 * 136]; // staged agg rows, padded
    int tid = threadIdx.x;
    for (int i = tid; i < 128 * 48; i += 256) {
        int k = i / 48, n = i % 48;
        Wt[n * 132 + k] = f2b((n < NC) ? W2[k * NC + n] : 0.f);
    }
    __syncthreads();

    int l = tid & 63, w = tid >> 6;
    int j = l & 15;                 // col-slice within node (8 cols each)
    int nloc = w * 4 + (l >> 4);    // node-local 0..15
    int lr = l & 15, g = l >> 4;

    for (int t = blockIdx.x; t < NT; t += gridDim.x) {
        int node = t * 16 + nloc;
        float di = dinv[node];
        float acc[8];
        {
            u16x8 v = *(const u16x8*)(h + (size_t)node * 128 + j * 8);
#pragma unroll
            for (int i = 0; i < 8; ++i) acc[i] = b2f(v[i]);
        }
        int beg = off[node], end = off[node + 1];
        int e = beg;
        int s0 = (e < end) ? eidx[e] : -1;
        int s1 = (e + 1 < end) ? eidx[e + 1] : -1;
        u16x8 r0 = zero8(), r1 = zero8();
        if (s0 >= 0) r0 = *(const u16x8*)(h + (size_t)s0 * 128 + j * 8);
        if (s1 >= 0) r1 = *(const u16x8*)(h + (size_t)s1 * 128 + j * 8);
        while (s0 >= 0) {
            int s2 = (e + 2 < end) ? eidx[e + 2] : -1;
            u16x8 r2 = zero8();
            if (s2 >= 0) r2 = *(const u16x8*)(h + (size_t)s2 * 128 + j * 8);
#pragma unroll
            for (int i = 0; i < 8; ++i) acc[i] += b2f(r0[i]);
            s0 = s1; s1 = s2; r0 = r1; r1 = r2; ++e;
        }
        // relu(di*acc + b1) -> LDS
        float4 blo = ((const float4*)b1)[j * 2];
        float4 bhi = ((const float4*)b1)[j * 2 + 1];
        u16x8 o;
        o[0] = f2b(fmaxf(acc[0] * di + blo.x, 0.f));
        o[1] = f2b(fmaxf(acc[1] * di + blo.y, 0.f));
        o[2] = f2b(fmaxf(acc[2] * di + blo.z, 0.f));
        o[3] = f2b(fmaxf(acc[3] * di + blo.w, 0.f));
        o[4] = f2b(fmaxf(acc[4] * di + bhi.x, 0.f));
        o[5] = f2b(fmaxf(acc[5] * di + bhi.y, 0.f));
        o[6] = f2b(fmaxf(acc[6] * di + bhi.z, 0.f));
        o[7] = f2b(fmaxf(acc[7] * di + bhi.w, 0.f));
        *(u16x8*)&rows[nloc * 136 + j * 8] = o;
        __syncthreads();

        if (w < 3) {  // col-tile w of 3 (48 cols)
            f32x4 a0 = {0.f, 0.f, 0.f, 0.f};
#pragma unroll
            for (int kt = 0; kt < 4; ++kt) {
                const unsigned short* pa = &rows[lr * 136 + kt * 32 + g * 4];
                short4 alo = *(const short4*)pa;
                short4 ahi = *(const short4*)(pa + 16);
                bf16x8 a;
                a[0] = alo.x; a[1] = alo.y; a[2] = alo.z; a[3] = alo.w;
                a[4] = ahi.x; a[5] = ahi.y; a[6] = ahi.z; a[7] = ahi.w;
                const unsigned short* pb = &Wt[(w * 16 + lr) * 132 + kt * 32 + g * 4];
                short4 wlo = *(const short4*)pb;
                short4 whi = *(const short4*)(pb + 16);
                bf16x8 b;
                b[0] = wlo.x; b[1] = wlo.y; b[2] = wlo.z; b[3] = wlo.w;
                b[4] = whi.x; b[5] = whi.y; b[6] = whi.z; b[7] = whi.w;
                a0 = __builtin_amdgcn_mfma_f32_16x16x32_bf16(a, b, a0, 0, 0, 0);
            }
            int rbase = t * 16 + g * 4;
#pragma unroll
            for (int i = 0; i < 4; ++i) {
                float dv = dinv[rbase + i];
                h2[(size_t)(rbase + i) * 64 + w * 16 + lr] = f2b(a0[i] * dv);
            }
        }
        __syncthreads();
    }
}

// ---------- gather2: out = log_softmax(di * (self + sum h2'[s]) + b2) ----------
// 2 nodes per wave; 4 groups x 8 lanes per node; 2-deep row prefetch.
__global__ __launch_bounds__(256, 8) void k_gather2(const unsigned short* __restrict__ h2,
                                                    float* __restrict__ out,
                                                    const int* __restrict__ off,
                                                    const int* __restrict__ eidx,
                                                    const float* __restrict__ dinv,
                                                    const float* __restrict__ b2, int N) {
    int node = blockIdx.x * 8 + (threadIdx.x >> 5);
    if (node >= N) return;
    int l = threadIdx.x & 31;
    int g = l >> 3, j = l & 7;
    bool act = (j < 6);
    float di = dinv[node];
    float acc[8];
#pragma unroll
    for (int i = 0; i < 8; ++i) acc[i] = 0.f;
    if (g == 0 && act) {
        u16x8 v = *(const u16x8*)(h2 + (size_t)node * 64 + j * 8);
#pragma unroll
        for (int i = 0; i < 8; ++i) acc[i] = b2f(v[i]);
    }
    int beg = off[node], end = off[node + 1];
    int e = beg + g;
    int s0 = (e < end) ? eidx[e] : -1;
    int s1 = (e + 4 < end) ? eidx[e + 4] : -1;
    u16x8 r0 = zero8(), r1 = zero8();
    if (s0 >= 0 && act) r0 = *(const u16x8*)(h2 + (size_t)s0 * 64 + j * 8);
    if (s1 >= 0 && act) r1 = *(const u16x8*)(h2 + (size_t)s1 * 64 + j * 8);
    while (s0 >= 0) {
        int s2 = (e + 8 < end) ? eidx[e + 8] : -1;
        u16x8 r2 = zero8();
        if (s2 >= 0 && act) r2 = *(const u16x8*)(h2 + (size_t)s2 * 64 + j * 8);
#pragma unroll
        for (int i = 0; i < 8; ++i) acc[i] += b2f(r0[i]);
        s0 = s1; s1 = s2; r0 = r1; r1 = r2; e += 4;
    }
#pragma unroll
    for (int i = 0; i < 8; ++i) acc[i] += __shfl_xor(acc[i], 8);
#pragma unroll
    for (int i = 0; i < 8; ++i) acc[i] += __shfl_xor(acc[i], 16);
    // all lanes in the 32-half hold identical col-slice sums for their j
    int c0 = j * 8;
    float vv[8];
#pragma unroll
    for (int i = 0; i < 8; ++i)
        vv[i] = (act && c0 + i < NC) ? acc[i] * di + b2[c0 + i] : -INFINITY;
    float m = vv[0];
#pragma unroll
    for (int i = 1; i < 8; ++i) m = fmaxf(m, vv[i]);
#pragma unroll
    for (int o = 4; o; o >>= 1) m = fmaxf(m, __shfl_xor(m, o));
    float sm = 0.f;
#pragma unroll
    for (int i = 0; i < 8; ++i) sm += (act && c0 + i < NC) ? expf(vv[i] - m) : 0.f;
#pragma unroll
    for (int o = 4; o; o >>= 1) sm += __shfl_xor(sm, o);
    float lg = logf(sm);
    if (g == 0 && act) {
#pragma unroll
        for (int i = 0; i < 8; ++i) {
            int c = c0 + i;
            if (c < NC) out[(size_t)node * NC + c] = vv[i] - m - lg;
        }
    }
}

extern "C" void kernel_launch(void* const* d_in, const int* in_sizes, int n_in,
                              void* d_out, int out_size, void* d_ws, size_t ws_size,
                              hipStream_t stream) {
    const float* x  = (const float*)d_in[0];
    const float* W1 = (const float*)d_in[1];
    const float* b1 = (const float*)d_in[2];
    const float* W2 = (const float*)d_in[3];
    const float* b2 = (const float*)d_in[4];
    const int*   ei = (const int*)d_in[5];
    const int* src = ei;
    const int* dst = ei + N_EDGES;
    float* out = (float*)d_out;

    char* ws = (char*)d_ws;
    int*   cnt  = (int*)ws;
    int*   off  = cnt + N_NODES + 32;
    int*   bsum = off + N_NODES + 32;
    float* dinv = (float*)(bsum + 512);
    int*   eidx = (int*)(dinv + N_NODES);
    unsigned short* h1 = (unsigned short*)(ws + (8u << 20));   // N*128 bf16 (pre-scaled)
    unsigned short* h2 = h1 + (size_t)N_NODES * 128;           // N*64 bf16 (pre-scaled)

    // CSR build
    hipMemsetAsync(cnt, 0, N_NODES * sizeof(int), stream);
    k_count<<<(N_EDGES + 255) / 256, 256, 0, stream>>>(dst, cnt, N_EDGES);
    k_blocksum<<<NB, 256, 0, stream>>>(cnt, bsum, dinv, N_NODES);
    k_scanb<<<1, 512, 0, stream>>>(bsum, NB);
    k_scanfinal<<<NB, 256, 0, stream>>>(cnt, bsum, off, N_NODES);
    k_scatter<<<(N_EDGES + 255) / 256, 256, 0, stream>>>(src, dst, cnt, eidx, N_EDGES);

    // layer 1 + layer-2 GEMM fused
    k_gemm1<<<1024, 256, 0, stream>>>(x, W1, dinv, h1);
    k_agg1mm<<<2048, 256, 0, stream>>>(h1, W2, dinv, b1, off, eidx, h2);

    // layer-2 aggregation + log_softmax
    k_gather2<<<(N_NODES + 7) / 8, 256, 0, stream>>>(h2, out, off, eidx, dinv, b2, N_NODES);
}